// Round 2
// baseline (143.699 us; speedup 1.0000x reference)
//
#include <hip/hip_runtime.h>

// Bahdanau additive attention, MI355X — full-f32 path (correctness-first).
// Shapes: B=8, TE=TD=256, HE=HD=512.
// d_in (f32): enc [B,TE,H], dec [B,TD,H], W_a [H,H], U_a [H,H], V_a [H,1]
// d_out (f32): c [B,TD,H] (1,048,576) then e [B,TD,TE] (524,288)
// d_ws: Ws f32 4MB | Uh f32 4MB | scores f32 2MB  (10MB total)

#define BB  8
#define TEE 256
#define TDD 256
#define HH  512

// tanh(x) = 1 - 2/(1+e^{2x});  e^{2x} = exp2(x * 2*log2(e))
__device__ __forceinline__ float tanh_fast(float x) {
  float t = __builtin_amdgcn_exp2f(x * 2.88539008177793f);
  return 1.0f - 2.0f * __builtin_amdgcn_rcpf(1.0f + t);
}

// ---------- phase 1: Ws = enc@W_a, Uh = dec@U_a (f32 VALU GEMM) ----------
// C[M=2048, N=512] = X[M,512] @ W[512,N]. Tile BM=128, BN=64, BK=16.
// block 256, thread computes 8x4. grid (16, 8, 2).
__global__ __launch_bounds__(256) void proj_f32(
    const float* __restrict__ enc, const float* __restrict__ dec,
    const float* __restrict__ Wa,  const float* __restrict__ Ua,
    float* __restrict__ Ws, float* __restrict__ Uh)
{
  __shared__ float saT[16][136];   // [k][m], padded
  __shared__ float sb [16][68];    // [k][n], padded
  const float* X = blockIdx.z ? dec : enc;
  const float* W = blockIdx.z ? Ua  : Wa;
  float*       Y = blockIdx.z ? Uh  : Ws;

  const int tid = threadIdx.x;
  const int m0 = blockIdx.x * 128, n0 = blockIdx.y * 64;
  const int tx = tid & 15;          // n quad: n = n0 + 4*tx + j
  const int ty = tid >> 4;          // m octet: m = m0 + 8*ty + i

  // staging indices
  const int am = tid >> 1, ah = (tid & 1) * 8;      // A: row, k-half
  const int bk = tid >> 4, bn = (tid & 15) * 4;     // B: k row, n quad

  float acc[8][4] = {};

  for (int k0 = 0; k0 < HH; k0 += 16) {
    float4 a0 = *(const float4*)(X + (size_t)(m0 + am) * HH + k0 + ah);
    float4 a1 = *(const float4*)(X + (size_t)(m0 + am) * HH + k0 + ah + 4);
    float4 bv = *(const float4*)(W + (size_t)(k0 + bk) * HH + n0 + bn);
    __syncthreads();
    saT[ah + 0][am] = a0.x; saT[ah + 1][am] = a0.y;
    saT[ah + 2][am] = a0.z; saT[ah + 3][am] = a0.w;
    saT[ah + 4][am] = a1.x; saT[ah + 5][am] = a1.y;
    saT[ah + 6][am] = a1.z; saT[ah + 7][am] = a1.w;
    *(float4*)&sb[bk][bn] = bv;
    __syncthreads();

    #pragma unroll
    for (int k = 0; k < 16; ++k) {
      float4 av0 = *(const float4*)&saT[k][ty * 8];
      float4 av1 = *(const float4*)&saT[k][ty * 8 + 4];
      float4 b   = *(const float4*)&sb[k][tx * 4];
      float a[8] = {av0.x, av0.y, av0.z, av0.w, av1.x, av1.y, av1.z, av1.w};
      #pragma unroll
      for (int i = 0; i < 8; ++i) {
        acc[i][0] += a[i] * b.x;
        acc[i][1] += a[i] * b.y;
        acc[i][2] += a[i] * b.z;
        acc[i][3] += a[i] * b.w;
      }
    }
  }
  #pragma unroll
  for (int i = 0; i < 8; ++i) {
    float4 o = {acc[i][0], acc[i][1], acc[i][2], acc[i][3]};
    *(float4*)(Y + (size_t)(m0 + ty * 8 + i) * HH + n0 + tx * 4) = o;
  }
}

// ---------- phase 2: scores[b,d,t] = sum_k tanh(Ws[b,t,k]+Uh[b,d,k]) * V[k] ----------
// grid (TE/16=16, TD/16=16, B=8), block 256. Tile: 16 t x 16 d, K chunks of 128.
__global__ __launch_bounds__(256) void score_kernel(
    const float* __restrict__ Ws, const float* __restrict__ Uh,
    const float* __restrict__ Va, float* __restrict__ scores)
{
  __shared__ float sw[16][132];
  __shared__ float su[16][132];
  __shared__ float sv[HH];

  const int b  = blockIdx.z;
  const int t0 = blockIdx.x * 16, d0 = blockIdx.y * 16;
  const int tid = threadIdx.x;
  const int t = tid & 15, d = tid >> 4;            // compute mapping
  const int srow = tid >> 4, scol = (tid & 15) * 8; // staging: coalesced rows

  { int i = tid * 2; sv[i] = Va[i]; sv[i + 1] = Va[i + 1]; }

  const float* wrow = Ws + (size_t)(b * TEE + t0 + srow) * HH + scol;
  const float* urow = Uh + (size_t)(b * TDD + d0 + srow) * HH + scol;

  float acc = 0.f;
  for (int k0 = 0; k0 < HH; k0 += 128) {
    float4 w0 = *(const float4*)(wrow + k0);
    float4 w1 = *(const float4*)(wrow + k0 + 4);
    float4 u0 = *(const float4*)(urow + k0);
    float4 u1 = *(const float4*)(urow + k0 + 4);
    __syncthreads();
    *(float4*)&sw[srow][scol]     = w0;
    *(float4*)&sw[srow][scol + 4] = w1;
    *(float4*)&su[srow][scol]     = u0;
    *(float4*)&su[srow][scol + 4] = u1;
    __syncthreads();

    const float* vv = sv + k0;
    #pragma unroll 8
    for (int kk = 0; kk < 128; kk += 4) {
      float4 w = *(const float4*)&sw[t][kk];
      float4 u = *(const float4*)&su[d][kk];
      float4 v = *(const float4*)(vv + kk);
      acc += tanh_fast(w.x + u.x) * v.x;
      acc += tanh_fast(w.y + u.y) * v.y;
      acc += tanh_fast(w.z + u.z) * v.z;
      acc += tanh_fast(w.w + u.w) * v.w;
    }
  }
  scores[(size_t)(b * TDD + d0 + d) * TEE + t0 + t] = acc;
}

// ---------- phase 3: softmax over t (f32 in ws -> f32 e in d_out) ----------
// grid 512, block 256 (4 waves, 1 row each)
__global__ __launch_bounds__(256) void softmax_kernel(
    const float* __restrict__ scores, float* __restrict__ e_out)
{
  const int wid = threadIdx.x >> 6, lane = threadIdx.x & 63;
  const int row = blockIdx.x * 4 + wid;            // 0 .. B*TD-1
  const float* sr = scores + (size_t)row * TEE;

  float x[4];
  #pragma unroll
  for (int j = 0; j < 4; ++j) x[j] = sr[lane + 64 * j];
  float m = fmaxf(fmaxf(x[0], x[1]), fmaxf(x[2], x[3]));
  #pragma unroll
  for (int off = 32; off; off >>= 1) m = fmaxf(m, __shfl_xor(m, off));

  float p[4], s = 0.f;
  #pragma unroll
  for (int j = 0; j < 4; ++j) {
    p[j] = __builtin_amdgcn_exp2f((x[j] - m) * 1.44269504088896f);
    s += p[j];
  }
  #pragma unroll
  for (int off = 32; off; off >>= 1) s += __shfl_xor(s, off);
  float r = __builtin_amdgcn_rcpf(s);

  float* er = e_out + (size_t)row * TEE;
  #pragma unroll
  for (int j = 0; j < 4; ++j) er[lane + 64 * j] = p[j] * r;
}

// ---------- phase 4: c[b,d,h] = sum_t e[b,d,t] * enc[b,t,h] (f32 VALU) ----------
// grid (TD/4=64, B=8), block 256. Block owns 4 d-rows; thread owns 2 h.
__global__ __launch_bounds__(256) void context_f32(
    const float* __restrict__ e, const float* __restrict__ enc,
    float* __restrict__ c)
{
  __shared__ float se[4][TEE];
  const int b  = blockIdx.y;
  const int d0 = blockIdx.x * 4;
  const int tid = threadIdx.x;

  {
    const int r = tid >> 6, q = (tid & 63) * 4;
    *(float4*)&se[r][q] = *(const float4*)(e + (size_t)(b * TDD + d0 + r) * TEE + q);
  }
  __syncthreads();

  float acc[4][2] = {};
  const float* encb = enc + (size_t)b * TEE * HH + tid * 2;
  #pragma unroll 4
  for (int t = 0; t < TEE; ++t) {
    float2 ev = *(const float2*)(encb + (size_t)t * HH);
    #pragma unroll
    for (int dd = 0; dd < 4; ++dd) {
      acc[dd][0] += se[dd][t] * ev.x;
      acc[dd][1] += se[dd][t] * ev.y;
    }
  }
  #pragma unroll
  for (int dd = 0; dd < 4; ++dd) {
    float2 o = {acc[dd][0], acc[dd][1]};
    *(float2*)(c + (size_t)(b * TDD + d0 + dd) * HH + tid * 2) = o;
  }
}

extern "C" void kernel_launch(void* const* d_in, const int* in_sizes, int n_in,
                              void* d_out, int out_size, void* d_ws, size_t ws_size,
                              hipStream_t stream) {
  const float* enc = (const float*)d_in[0];
  const float* dec = (const float*)d_in[1];
  const float* Wa  = (const float*)d_in[2];
  const float* Ua  = (const float*)d_in[3];
  const float* Va  = (const float*)d_in[4];

  float* c_out = (float*)d_out;                          // f32 c [B*TD*H]
  float* e_out = c_out + (size_t)BB * TDD * HH;          // f32 e [B*TD*TE]

  float* Ws     = (float*)d_ws;                          // f32 [B*TE*H]  4MB
  float* Uh     = Ws + (size_t)BB * TEE * HH;            // f32 [B*TD*H]  4MB
  float* scores = Uh + (size_t)BB * TDD * HH;            // f32 [B*TD*TE] 2MB

  proj_f32     <<<dim3(16, 8, 2),  256, 0, stream>>>(enc, dec, Wa, Ua, Ws, Uh);
  score_kernel <<<dim3(16, 16, 8), 256, 0, stream>>>(Ws, Uh, Va, scores);
  softmax_kernel<<<512,            256, 0, stream>>>(scores, e_out);
  context_f32  <<<dim3(64, 8),     256, 0, stream>>>(e_out, enc, c_out);
}

// Round 3
// 107.803 us; speedup vs baseline: 1.3330x; 1.3330x over previous
//
#include <hip/hip_runtime.h>

// Bahdanau additive attention, MI355X.
// Shapes: B=8, TE=TD=256, HE=HD=512.
// d_in (f32): enc [B,TE,H], dec [B,TD,H], W_a [H,H], U_a [H,H], V_a [H,1]
// d_out (f32): c [B,TD,H] (1,048,576) then e [B,TD,TE] (524,288)
// d_ws: WsS f32 4MB | UhS f32 4MB | A f32 2MB ; e_bf16 (1MB) overlays WsS after scores.
//
// Math: tanh(x) = 1 - 2/(1+e^{2x}); e^{2x} = exp2(x * 2log2e).
// WsS/UhS are pre-scaled by 2log2e, so score work per element is
// add, exp2, add, rcp, fma. Sum_k V_k is constant over the softmax axis ->
// dropped (softmax shift invariance); softmax uses min and folds the -2.

#define BB  8
#define TEE 256
#define TDD 256
#define HH  512
#define C2LOG2E 2.8853900817779268f   // 2*log2(e)

typedef __attribute__((ext_vector_type(8))) short  short8;
typedef __attribute__((ext_vector_type(4))) float  floatx4;

__device__ __forceinline__ unsigned short f2bf(float f) {
  unsigned int u = __builtin_bit_cast(unsigned int, f);
  u += 0x7FFFu + ((u >> 16) & 1u);            // RNE
  return (unsigned short)(u >> 16);
}

// ---------- phase 1: WsS = (enc@W_a)*2log2e, UhS = (dec@U_a)*2log2e ----------
// bf16 MFMA 16x16x32, f32 out. grid (128, 32, 2), block 64.
__global__ __launch_bounds__(64) void proj_mfma(
    const float* __restrict__ enc, const float* __restrict__ dec,
    const float* __restrict__ Wa,  const float* __restrict__ Ua,
    float* __restrict__ WsS, float* __restrict__ UhS)
{
  const float* X = blockIdx.z ? dec : enc;
  const float* W = blockIdx.z ? Ua  : Wa;
  float*       Y = blockIdx.z ? UhS : WsS;
  const int lane = threadIdx.x;
  const int m0 = blockIdx.x * 16, n0 = blockIdx.y * 16;
  const int r15 = lane & 15, g = lane >> 4;

  floatx4 acc = {0.f, 0.f, 0.f, 0.f};
  for (int k0 = 0; k0 < HH; k0 += 32) {
    const float* ap = X + (size_t)(m0 + r15) * HH + k0 + g * 8;
    float4 a0 = *(const float4*)ap;
    float4 a1 = *(const float4*)(ap + 4);
    short8 a, b;
    a[0] = (short)f2bf(a0.x * C2LOG2E); a[1] = (short)f2bf(a0.y * C2LOG2E);
    a[2] = (short)f2bf(a0.z * C2LOG2E); a[3] = (short)f2bf(a0.w * C2LOG2E);
    a[4] = (short)f2bf(a1.x * C2LOG2E); a[5] = (short)f2bf(a1.y * C2LOG2E);
    a[6] = (short)f2bf(a1.z * C2LOG2E); a[7] = (short)f2bf(a1.w * C2LOG2E);
    const float* bp = W + (size_t)(k0 + g * 8) * HH + n0 + r15;
    #pragma unroll
    for (int j = 0; j < 8; ++j) b[j] = (short)f2bf(bp[(size_t)j * HH]);
    acc = __builtin_amdgcn_mfma_f32_16x16x32_bf16(a, b, acc, 0, 0, 0);
  }
  // D: col = lane&15, row = (lane>>4)*4 + reg   [m89-verified]
  float* yp = Y + (size_t)(m0 + g * 4) * HH + n0 + r15;
  #pragma unroll
  for (int r = 0; r < 4; ++r) yp[(size_t)r * HH] = acc[r];
}

// ---------- phase 2: A[b,d,t] = sum_k Va[k] * rcp(1 + exp2(wS+uS)) ----------
// score_true = Sv - 2A; Sv constant over t -> dropped. grid (16,16,8), block 256.
__global__ __launch_bounds__(256) void score_kernel(
    const float* __restrict__ WsS, const float* __restrict__ UhS,
    const float* __restrict__ Va, float* __restrict__ A)
{
  __shared__ float sw[16][132];
  __shared__ float su[16][132];

  const int b  = blockIdx.z;
  const int t0 = blockIdx.x * 16, d0 = blockIdx.y * 16;
  const int tid = threadIdx.x;
  const int t = tid & 15, d = tid >> 4;             // compute mapping
  const int srow = tid >> 4, scol = (tid & 15) * 8; // staging mapping

  const float* wrow = WsS + (size_t)(b * TEE + t0 + srow) * HH + scol;
  const float* urow = UhS + (size_t)(b * TDD + d0 + srow) * HH + scol;

  float ac0 = 0.f, ac1 = 0.f, ac2 = 0.f, ac3 = 0.f;
  float ac4 = 0.f, ac5 = 0.f, ac6 = 0.f, ac7 = 0.f;

  for (int k0 = 0; k0 < HH; k0 += 128) {
    float4 w0 = *(const float4*)(wrow + k0);
    float4 w1 = *(const float4*)(wrow + k0 + 4);
    float4 u0 = *(const float4*)(urow + k0);
    float4 u1 = *(const float4*)(urow + k0 + 4);
    __syncthreads();
    *(float4*)&sw[srow][scol]     = w0;
    *(float4*)&sw[srow][scol + 4] = w1;
    *(float4*)&su[srow][scol]     = u0;
    *(float4*)&su[srow][scol + 4] = u1;
    __syncthreads();

#define TERM(W_, U_, V_, AC_) { \
    float z_ = __builtin_amdgcn_exp2f((W_) + (U_)); \
    float r_ = __builtin_amdgcn_rcpf(1.0f + z_);    \
    AC_ = fmaf((V_), r_, AC_); }

    #pragma unroll 4
    for (int kk = 0; kk < 128; kk += 8) {
      float4 wA = *(const float4*)&sw[t][kk];
      float4 wB = *(const float4*)&sw[t][kk + 4];
      float4 uA = *(const float4*)&su[d][kk];
      float4 uB = *(const float4*)&su[d][kk + 4];
      float4 vA = *(const float4*)(Va + k0 + kk);      // uniform -> s_load
      float4 vB = *(const float4*)(Va + k0 + kk + 4);
      TERM(wA.x, uA.x, vA.x, ac0) TERM(wA.y, uA.y, vA.y, ac1)
      TERM(wA.z, uA.z, vA.z, ac2) TERM(wA.w, uA.w, vA.w, ac3)
      TERM(wB.x, uB.x, vB.x, ac4) TERM(wB.y, uB.y, vB.y, ac5)
      TERM(wB.z, uB.z, vB.z, ac6) TERM(wB.w, uB.w, vB.w, ac7)
    }
#undef TERM
  }
  float s = ((ac0 + ac1) + (ac2 + ac3)) + ((ac4 + ac5) + (ac6 + ac7));
  A[(size_t)(b * TDD + d0 + d) * TEE + t0 + t] = s;
}

// ---------- phase 3: softmax over t of (Sv - 2A) == min-softmax of A ----------
// e f32 -> d_out; e bf16 -> ws (for context MFMA). grid 512, block 256.
__global__ __launch_bounds__(256) void softmax_kernel(
    const float* __restrict__ A, float* __restrict__ e_out,
    unsigned short* __restrict__ e_bf)
{
  const int wid = threadIdx.x >> 6, lane = threadIdx.x & 63;
  const int row = blockIdx.x * 4 + wid;            // 0 .. B*TD-1
  const float* sr = A + (size_t)row * TEE;

  float x[4];
  #pragma unroll
  for (int j = 0; j < 4; ++j) x[j] = sr[lane + 64 * j];
  float m = fminf(fminf(x[0], x[1]), fminf(x[2], x[3]));
  #pragma unroll
  for (int off = 32; off; off >>= 1) m = fminf(m, __shfl_xor(m, off));

  float p[4], s = 0.f;
  #pragma unroll
  for (int j = 0; j < 4; ++j) {
    p[j] = __builtin_amdgcn_exp2f(C2LOG2E * (m - x[j]));  // exp(score - max)
    s += p[j];
  }
  #pragma unroll
  for (int off = 32; off; off >>= 1) s += __shfl_xor(s, off);
  float r = __builtin_amdgcn_rcpf(s);

  float*          er = e_out + (size_t)row * TEE;
  unsigned short* eb = e_bf  + (size_t)row * TEE;
  #pragma unroll
  for (int j = 0; j < 4; ++j) {
    float v = p[j] * r;
    er[lane + 64 * j] = v;
    eb[lane + 64 * j] = f2bf(v);
  }
}

// ---------- phase 4: c[b,d,h] = sum_t e[b,d,t] * enc[b,t,h] (bf16 MFMA) ----------
// grid (16, 32, 8), block 64.
__global__ __launch_bounds__(64) void context_mfma(
    const unsigned short* __restrict__ e_bf, const float* __restrict__ enc,
    float* __restrict__ c)
{
  const int lane = threadIdx.x;
  const int b = blockIdx.z;
  const int d0 = blockIdx.x * 16, h0 = blockIdx.y * 16;
  const int r15 = lane & 15, g = lane >> 4;

  floatx4 acc = {0.f, 0.f, 0.f, 0.f};
  const unsigned short* ep = e_bf + (size_t)(b * TDD + d0 + r15) * TEE + g * 8;
  for (int k0 = 0; k0 < TEE; k0 += 32) {
    short8 a = *(const short8*)(ep + k0);
    const float* bp = enc + (size_t)(b * TEE + k0 + g * 8) * HH + h0 + r15;
    short8 bb;
    #pragma unroll
    for (int j = 0; j < 8; ++j) bb[j] = (short)f2bf(bp[(size_t)j * HH]);
    acc = __builtin_amdgcn_mfma_f32_16x16x32_bf16(a, bb, acc, 0, 0, 0);
  }
  float* cp = c + (size_t)(b * TDD + d0 + g * 4) * HH + h0 + r15;
  #pragma unroll
  for (int r = 0; r < 4; ++r) cp[(size_t)r * HH] = acc[r];
}

extern "C" void kernel_launch(void* const* d_in, const int* in_sizes, int n_in,
                              void* d_out, int out_size, void* d_ws, size_t ws_size,
                              hipStream_t stream) {
  const float* enc = (const float*)d_in[0];
  const float* dec = (const float*)d_in[1];
  const float* Wa  = (const float*)d_in[2];
  const float* Ua  = (const float*)d_in[3];
  const float* Va  = (const float*)d_in[4];

  float* c_out = (float*)d_out;                          // f32 c [B*TD*H]
  float* e_out = c_out + (size_t)BB * TDD * HH;          // f32 e [B*TD*TE]

  float* WsS = (float*)d_ws;                             // f32 [B*TE*H]  4MB
  float* UhS = WsS + (size_t)BB * TEE * HH;              // f32 [B*TD*H]  4MB
  float* Asc = UhS + (size_t)BB * TDD * HH;              // f32 [B*TD*TE] 2MB
  unsigned short* e_bf = (unsigned short*)WsS;           // overlays WsS (dead)

  proj_mfma     <<<dim3(128, 32, 2), 64, 0, stream>>>(enc, dec, Wa, Ua, WsS, UhS);
  score_kernel  <<<dim3(16, 16, 8), 256, 0, stream>>>(WsS, UhS, Va, Asc);
  softmax_kernel<<<512,             256, 0, stream>>>(Asc, e_out, e_bf);
  context_mfma  <<<dim3(16, 32, 8),  64, 0, stream>>>(e_bf, enc, c_out);
}

// Round 4
// 81.500 us; speedup vs baseline: 1.7632x; 1.3227x over previous
//
#include <hip/hip_runtime.h>

// Bahdanau additive attention, MI355X.  B=8, TE=TD=256, HE=HD=512.
// d_in (f32): enc [B,TE,H], dec [B,TD,H], W_a [H,H], U_a [H,H], V_a [H,1]
// d_out (f32): c [B,TD,H] | e [B,TD,TE]
//
// Math: tanh(x) = 1 - 2/(1+e^{2x}).  score = Sv - 2*A where
// A[d,t] = sum_k Va[k]/(1 + EW[t,k]*EU[d,k]),  EW = exp2(2log2e * enc@Wa),
// EU likewise.  Sv is constant over t -> dropped (softmax shift-invariance);
// softmax uses min and folds the -2 into the exp2 constant.
// Inner score body: fma, rcp, fma  (12 cy/elem issue).
//
// ws (9MB): WTa bf16 512K | WTu bf16 512K | EW f32 4M | EU f32 4M
//           encT bf16 2M overlays EU after score.
// A (scores) uses d_out's e-region; softmax is in-place.

#define BB  8
#define TEE 256
#define TDD 256
#define HH  512
#define C2LOG2E 2.8853900817779268f   // 2*log2(e)

typedef __attribute__((ext_vector_type(8))) short  short8;
typedef __attribute__((ext_vector_type(4))) float  floatx4;

__device__ __forceinline__ unsigned short f2bf(float f) {
  unsigned int u = __builtin_bit_cast(unsigned int, f);
  u += 0x7FFFu + ((u >> 16) & 1u);            // RNE
  return (unsigned short)(u >> 16);
}

// ---------- prep A: WT[n][k] = bf16(W[k][n] * 2log2e). grid (8,8,2), block 256 ----------
__global__ __launch_bounds__(256) void transpose_w(
    const float* __restrict__ Wa, const float* __restrict__ Ua,
    unsigned short* __restrict__ WTa, unsigned short* __restrict__ WTu)
{
  __shared__ float tile[64][65];
  const float* W = blockIdx.z ? Ua : Wa;
  unsigned short* WT = blockIdx.z ? WTu : WTa;
  const int k0 = blockIdx.x * 64, n0 = blockIdx.y * 64;
  const int c = threadIdx.x & 63, r4 = threadIdx.x >> 6;
  #pragma unroll
  for (int i = 0; i < 16; ++i) {
    int kr = i * 4 + r4;
    tile[kr][c] = W[(size_t)(k0 + kr) * HH + n0 + c];
  }
  __syncthreads();
  #pragma unroll
  for (int i = 0; i < 16; ++i) {
    int nr = i * 4 + r4;
    WT[(size_t)(n0 + nr) * HH + k0 + c] = f2bf(tile[c][nr] * C2LOG2E);
  }
}

// ---------- prep B: encT[b][h][t] = bf16(enc[b][t][h]). grid (8,4,8), block 256 ----------
// Runs AFTER score (overlays dead EU region).
__global__ __launch_bounds__(256) void transpose_enc(
    const float* __restrict__ enc, unsigned short* __restrict__ encT)
{
  __shared__ float tile[64][65];
  const int b = blockIdx.z;
  const int h0 = blockIdx.x * 64, t0 = blockIdx.y * 64;
  const int c = threadIdx.x & 63, r4 = threadIdx.x >> 6;
  #pragma unroll
  for (int i = 0; i < 16; ++i) {
    int tr = i * 4 + r4;
    tile[tr][c] = enc[((size_t)b * TEE + t0 + tr) * HH + h0 + c];
  }
  __syncthreads();
  #pragma unroll
  for (int i = 0; i < 16; ++i) {
    int hr = i * 4 + r4;
    encT[((size_t)b * HH + h0 + hr) * TEE + t0 + c] = f2bf(tile[c][hr]);
  }
}

// ---------- phase 1: EW = exp2(X @ WT^T), bf16 MFMA, direct global frags ----------
// grid (32, 8, 2), block 256 = 4 waves; wave w: rows m0+w*16.., cols n0..n0+64.
__global__ __launch_bounds__(256) void proj_exp(
    const float* __restrict__ enc, const float* __restrict__ dec,
    const unsigned short* __restrict__ WTa, const unsigned short* __restrict__ WTu,
    float* __restrict__ EW, float* __restrict__ EU)
{
  const float* X = blockIdx.z ? dec : enc;
  const unsigned short* WT = blockIdx.z ? WTu : WTa;
  float* Y = blockIdx.z ? EU : EW;
  const int lane = threadIdx.x & 63, w = threadIdx.x >> 6;
  const int m0 = blockIdx.x * 64 + w * 16, n0 = blockIdx.y * 64;
  const int r15 = lane & 15, g = lane >> 4;

  floatx4 acc[4] = {{0.f,0.f,0.f,0.f},{0.f,0.f,0.f,0.f},
                    {0.f,0.f,0.f,0.f},{0.f,0.f,0.f,0.f}};
  const float* ap = X + (size_t)(m0 + r15) * HH + g * 8;
  const unsigned short* bp0 = WT + (size_t)(n0 + r15) * HH + g * 8;

  for (int k0 = 0; k0 < HH; k0 += 32) {
    float4 a0 = *(const float4*)(ap + k0);
    float4 a1 = *(const float4*)(ap + k0 + 4);
    short8 a;
    a[0]=(short)f2bf(a0.x); a[1]=(short)f2bf(a0.y);
    a[2]=(short)f2bf(a0.z); a[3]=(short)f2bf(a0.w);
    a[4]=(short)f2bf(a1.x); a[5]=(short)f2bf(a1.y);
    a[6]=(short)f2bf(a1.z); a[7]=(short)f2bf(a1.w);
    #pragma unroll
    for (int nt = 0; nt < 4; ++nt) {
      short8 bv = *(const short8*)(bp0 + (size_t)nt * 16 * HH + k0);
      acc[nt] = __builtin_amdgcn_mfma_f32_16x16x32_bf16(a, bv, acc[nt], 0, 0, 0);
    }
  }
  // D: col = lane&15, row = (lane>>4)*4 + reg  [m89-verified]
  #pragma unroll
  for (int nt = 0; nt < 4; ++nt) {
    float* yp = Y + (size_t)(m0 + g * 4) * HH + n0 + nt * 16 + r15;
    #pragma unroll
    for (int r = 0; r < 4; ++r) {
      float v = fminf(fmaxf(acc[nt][r], -126.f), 126.f);  // keep EW finite&nonzero
      yp[(size_t)r * HH] = __builtin_amdgcn_exp2f(v);
    }
  }
}

// ---------- phase 2: A[b,d,t] = sum_k Va[k] * rcp(1 + EW[t,k]*EU[d,k]) ----------
// grid (16,16,8), block 256.  Writes into d_out's e-region.
__global__ __launch_bounds__(256) void score_kernel(
    const float* __restrict__ EW, const float* __restrict__ EU,
    const float* __restrict__ Va, float* __restrict__ A)
{
  __shared__ float sw[16][132];
  __shared__ float su[16][132];

  const int b  = blockIdx.z;
  const int t0 = blockIdx.x * 16, d0 = blockIdx.y * 16;
  const int tid = threadIdx.x;
  const int t = tid & 15, d = tid >> 4;             // compute mapping
  const int srow = tid >> 4, scol = (tid & 15) * 8; // staging mapping

  const float* wrow = EW + (size_t)(b * TEE + t0 + srow) * HH + scol;
  const float* urow = EU + (size_t)(b * TDD + d0 + srow) * HH + scol;

  float ac0 = 0.f, ac1 = 0.f, ac2 = 0.f, ac3 = 0.f;
  float ac4 = 0.f, ac5 = 0.f, ac6 = 0.f, ac7 = 0.f;

  for (int k0 = 0; k0 < HH; k0 += 128) {
    float4 w0 = *(const float4*)(wrow + k0);
    float4 w1 = *(const float4*)(wrow + k0 + 4);
    float4 u0 = *(const float4*)(urow + k0);
    float4 u1 = *(const float4*)(urow + k0 + 4);
    __syncthreads();
    *(float4*)&sw[srow][scol]     = w0;
    *(float4*)&sw[srow][scol + 4] = w1;
    *(float4*)&su[srow][scol]     = u0;
    *(float4*)&su[srow][scol + 4] = u1;
    __syncthreads();

#define TERM(W_, U_, V_, AC_) { \
    float z_ = fmaf((W_), (U_), 1.0f);           \
    float r_ = __builtin_amdgcn_rcpf(z_);        \
    AC_ = fmaf((V_), r_, AC_); }

    #pragma unroll 4
    for (int kk = 0; kk < 128; kk += 8) {
      float4 wA = *(const float4*)&sw[t][kk];
      float4 wB = *(const float4*)&sw[t][kk + 4];
      float4 uA = *(const float4*)&su[d][kk];
      float4 uB = *(const float4*)&su[d][kk + 4];
      float4 vA = *(const float4*)(Va + k0 + kk);      // uniform -> s_load
      float4 vB = *(const float4*)(Va + k0 + kk + 4);
      TERM(wA.x, uA.x, vA.x, ac0) TERM(wA.y, uA.y, vA.y, ac1)
      TERM(wA.z, uA.z, vA.z, ac2) TERM(wA.w, uA.w, vA.w, ac3)
      TERM(wB.x, uB.x, vB.x, ac4) TERM(wB.y, uB.y, vB.y, ac5)
      TERM(wB.z, uB.z, vB.z, ac6) TERM(wB.w, uB.w, vB.w, ac7)
    }
#undef TERM
  }
  float s = ((ac0 + ac1) + (ac2 + ac3)) + ((ac4 + ac5) + (ac6 + ac7));
  A[(size_t)(b * TDD + d0 + d) * TEE + t0 + t] = s;
}

// ---------- phase 3: in-place min-softmax of A over t. grid 512, block 256 ----------
__global__ __launch_bounds__(256) void softmax_kernel(float* __restrict__ e)
{
  const int wid = threadIdx.x >> 6, lane = threadIdx.x & 63;
  const int row = blockIdx.x * 4 + wid;            // 0 .. B*TD-1
  float* er = e + (size_t)row * TEE;

  float x[4];
  #pragma unroll
  for (int j = 0; j < 4; ++j) x[j] = er[lane + 64 * j];
  float m = fminf(fminf(x[0], x[1]), fminf(x[2], x[3]));
  #pragma unroll
  for (int off = 32; off; off >>= 1) m = fminf(m, __shfl_xor(m, off));

  float p[4], s = 0.f;
  #pragma unroll
  for (int j = 0; j < 4; ++j) {
    p[j] = __builtin_amdgcn_exp2f(C2LOG2E * (m - x[j]));  // exp(score - max)
    s += p[j];
  }
  #pragma unroll
  for (int off = 32; off; off >>= 1) s += __shfl_xor(s, off);
  float r = __builtin_amdgcn_rcpf(s);

  #pragma unroll
  for (int j = 0; j < 4; ++j) er[lane + 64 * j] = p[j] * r;
}

// ---------- phase 4: c[b,d,h] = sum_t e[b,d,t]*enc[b,t,h], bf16 MFMA ----------
// grid (16, 8, 8), block 64; wave: 16 d x 64 h, B-frags from encT.
__global__ __launch_bounds__(64) void context_mfma(
    const float* __restrict__ e, const unsigned short* __restrict__ encT,
    float* __restrict__ c)
{
  const int lane = threadIdx.x;
  const int b = blockIdx.z;
  const int d0 = blockIdx.x * 16, h0 = blockIdx.y * 64;
  const int r15 = lane & 15, g = lane >> 4;

  floatx4 acc[4] = {{0.f,0.f,0.f,0.f},{0.f,0.f,0.f,0.f},
                    {0.f,0.f,0.f,0.f},{0.f,0.f,0.f,0.f}};
  const float* ep = e + (size_t)(b * TDD + d0 + r15) * TEE + g * 8;
  const unsigned short* bp0 = encT + ((size_t)b * HH + h0 + r15) * TEE + g * 8;

  for (int k0 = 0; k0 < TEE; k0 += 32) {
    float4 e0 = *(const float4*)(ep + k0);
    float4 e1 = *(const float4*)(ep + k0 + 4);
    short8 a;
    a[0]=(short)f2bf(e0.x); a[1]=(short)f2bf(e0.y);
    a[2]=(short)f2bf(e0.z); a[3]=(short)f2bf(e0.w);
    a[4]=(short)f2bf(e1.x); a[5]=(short)f2bf(e1.y);
    a[6]=(short)f2bf(e1.z); a[7]=(short)f2bf(e1.w);
    #pragma unroll
    for (int nt = 0; nt < 4; ++nt) {
      short8 bv = *(const short8*)(bp0 + (size_t)nt * 16 * TEE + k0);
      acc[nt] = __builtin_amdgcn_mfma_f32_16x16x32_bf16(a, bv, acc[nt], 0, 0, 0);
    }
  }
  #pragma unroll
  for (int nt = 0; nt < 4; ++nt) {
    float* cp = c + (size_t)(b * TDD + d0 + g * 4) * HH + h0 + nt * 16 + r15;
    #pragma unroll
    for (int r = 0; r < 4; ++r) cp[(size_t)r * HH] = acc[nt][r];
  }
}

extern "C" void kernel_launch(void* const* d_in, const int* in_sizes, int n_in,
                              void* d_out, int out_size, void* d_ws, size_t ws_size,
                              hipStream_t stream) {
  const float* enc = (const float*)d_in[0];
  const float* dec = (const float*)d_in[1];
  const float* Wa  = (const float*)d_in[2];
  const float* Ua  = (const float*)d_in[3];
  const float* Va  = (const float*)d_in[4];

  float* c_out = (float*)d_out;                          // f32 c [B*TD*H]
  float* e_out = c_out + (size_t)BB * TDD * HH;          // f32 e [B*TD*TE] (also A)

  unsigned short* WTa = (unsigned short*)d_ws;           // bf16 [512*512] 512KB
  unsigned short* WTu = WTa + (size_t)HH * HH;           // bf16 [512*512] 512KB
  float* EW = (float*)(WTu + (size_t)HH * HH);           // f32 [2048*512] 4MB
  float* EU = EW + (size_t)BB * TEE * HH;                // f32 [2048*512] 4MB
  unsigned short* encT = (unsigned short*)EU;            // bf16 2MB, overlays EU after score

  transpose_w   <<<dim3(8, 8, 2),   256, 0, stream>>>(Wa, Ua, WTa, WTu);
  proj_exp      <<<dim3(32, 8, 2),  256, 0, stream>>>(enc, dec, WTa, WTu, EW, EU);
  score_kernel  <<<dim3(16, 16, 8), 256, 0, stream>>>(EW, EU, Va, e_out);
  transpose_enc <<<dim3(8, 4, 8),   256, 0, stream>>>(enc, encT);     // EU now dead
  softmax_kernel<<<512,             256, 0, stream>>>(e_out);
  context_mfma  <<<dim3(16, 8, 8),   64, 0, stream>>>(e_out, encT, c_out);
}

// Round 5
// 75.254 us; speedup vs baseline: 1.9095x; 1.0830x over previous
//
#include <hip/hip_runtime.h>

// Bahdanau additive attention, MI355X.  B=8, TE=TD=256, HE=HD=512.
// d_in (f32): enc [B,TE,H], dec [B,TD,H], W_a [H,H], U_a [H,H], V_a [H,1]
// d_out (f32): c [B,TD,H] | e [B,TD,TE]
//
// Math: tanh(x) = 1 - 2/(1+e^{2x}).  score = Sv - 2*A,
// A[d,t] = sum_k Va[k]/(1 + EW[t,k]*EU[d,k]),  EW = exp2(2log2e * enc@Wa), EU likewise.
// Sv is const over t -> dropped (softmax shift invariance); softmax over min(A),
// folding the -2 into the exp2 constant.
//
// ws (256MB available; we use ~13MB):
//   WTa bf16 512K | WTu bf16 512K | encT bf16 2M | EW f32 4M | EU f32 4M | A f32 2M
//
// Kernels: prep (transposes) -> proj_exp -> score_db -> ctx_fused(softmax+PV).

#define BB  8
#define TEE 256
#define TDD 256
#define HH  512
#define C2LOG2E 2.8853900817779268f   // 2*log2(e)

typedef __attribute__((ext_vector_type(8))) short  short8;
typedef __attribute__((ext_vector_type(4))) float  floatx4;

__device__ __forceinline__ unsigned short f2bf(float f) {
  unsigned int u = __builtin_bit_cast(unsigned int, f);
  u += 0x7FFFu + ((u >> 16) & 1u);            // RNE
  return (unsigned short)(u >> 16);
}

// ---------- prep: WT[n][k]=bf16(W[k][n]*2log2e); encT[b][h][t]=bf16(enc[b][t][h]) ----------
// grid (8, 8, 10): z<2 -> W/U transpose (xy tile 512x512); z>=2 -> enc batch z-2 (skip y>=4).
__global__ __launch_bounds__(256) void prep_kernel(
    const float* __restrict__ Wa, const float* __restrict__ Ua,
    const float* __restrict__ enc,
    unsigned short* __restrict__ WTa, unsigned short* __restrict__ WTu,
    unsigned short* __restrict__ encT)
{
  __shared__ float tile[64][65];
  const int c = threadIdx.x & 63, r4 = threadIdx.x >> 6;
  const int z = blockIdx.z;

  if (z < 2) {
    const float* W = z ? Ua : Wa;
    unsigned short* WT = z ? WTu : WTa;
    const int k0 = blockIdx.x * 64, n0 = blockIdx.y * 64;
    #pragma unroll
    for (int i = 0; i < 16; ++i) {
      int kr = i * 4 + r4;
      tile[kr][c] = W[(size_t)(k0 + kr) * HH + n0 + c];
    }
    __syncthreads();
    #pragma unroll
    for (int i = 0; i < 16; ++i) {
      int nr = i * 4 + r4;
      WT[(size_t)(n0 + nr) * HH + k0 + c] = f2bf(tile[c][nr] * C2LOG2E);
    }
  } else {
    if (blockIdx.y >= 4) return;
    const int b = z - 2;
    const int h0 = blockIdx.x * 64, t0 = blockIdx.y * 64;
    #pragma unroll
    for (int i = 0; i < 16; ++i) {
      int tr = i * 4 + r4;
      tile[tr][c] = enc[((size_t)b * TEE + t0 + tr) * HH + h0 + c];
    }
    __syncthreads();
    #pragma unroll
    for (int i = 0; i < 16; ++i) {
      int hr = i * 4 + r4;
      encT[((size_t)b * HH + h0 + hr) * TEE + t0 + c] = f2bf(tile[c][hr]);
    }
  }
}

// ---------- phase 1: EW = exp2(X @ WT^T), bf16 MFMA, direct global frags ----------
// grid (32, 8, 2), block 256 = 4 waves; wave w: rows m0+w*16.., cols n0..n0+64.
__global__ __launch_bounds__(256) void proj_exp(
    const float* __restrict__ enc, const float* __restrict__ dec,
    const unsigned short* __restrict__ WTa, const unsigned short* __restrict__ WTu,
    float* __restrict__ EW, float* __restrict__ EU)
{
  const float* X = blockIdx.z ? dec : enc;
  const unsigned short* WT = blockIdx.z ? WTu : WTa;
  float* Y = blockIdx.z ? EU : EW;
  const int lane = threadIdx.x & 63, w = threadIdx.x >> 6;
  const int m0 = blockIdx.x * 64 + w * 16, n0 = blockIdx.y * 64;
  const int r15 = lane & 15, g = lane >> 4;

  floatx4 acc[4] = {{0.f,0.f,0.f,0.f},{0.f,0.f,0.f,0.f},
                    {0.f,0.f,0.f,0.f},{0.f,0.f,0.f,0.f}};
  const float* ap = X + (size_t)(m0 + r15) * HH + g * 8;
  const unsigned short* bp0 = WT + (size_t)(n0 + r15) * HH + g * 8;

  for (int k0 = 0; k0 < HH; k0 += 32) {
    float4 a0 = *(const float4*)(ap + k0);
    float4 a1 = *(const float4*)(ap + k0 + 4);
    short8 a;
    a[0]=(short)f2bf(a0.x); a[1]=(short)f2bf(a0.y);
    a[2]=(short)f2bf(a0.z); a[3]=(short)f2bf(a0.w);
    a[4]=(short)f2bf(a1.x); a[5]=(short)f2bf(a1.y);
    a[6]=(short)f2bf(a1.z); a[7]=(short)f2bf(a1.w);
    #pragma unroll
    for (int nt = 0; nt < 4; ++nt) {
      short8 bv = *(const short8*)(bp0 + (size_t)nt * 16 * HH + k0);
      acc[nt] = __builtin_amdgcn_mfma_f32_16x16x32_bf16(a, bv, acc[nt], 0, 0, 0);
    }
  }
  // D: col = lane&15, row = (lane>>4)*4 + reg  [m89-verified]
  #pragma unroll
  for (int nt = 0; nt < 4; ++nt) {
    float* yp = Y + (size_t)(m0 + g * 4) * HH + n0 + nt * 16 + r15;
    #pragma unroll
    for (int r = 0; r < 4; ++r) {
      float v = fminf(fmaxf(acc[nt][r], -126.f), 126.f);  // finite & nonzero
      yp[(size_t)r * HH] = __builtin_amdgcn_exp2f(v);
    }
  }
}

// ---------- phase 2: A[b,d,t] = sum_k Va[k] * rcp(1 + EW[t,k]*EU[d,k]) ----------
// Double-buffered LDS, loads-issued-before-compute. grid (16,16,8), block 256.
__global__ __launch_bounds__(256) void score_db(
    const float* __restrict__ EW, const float* __restrict__ EU,
    const float* __restrict__ Va, float* __restrict__ A)
{
  __shared__ float sw[2][16][132];
  __shared__ float su[2][16][132];

  const int b  = blockIdx.z;
  const int t0 = blockIdx.x * 16, d0 = blockIdx.y * 16;
  const int tid = threadIdx.x;
  const int t = tid & 15, d = tid >> 4;             // compute mapping
  const int srow = tid >> 4, scol = (tid & 15) * 8; // staging mapping

  const float* wrow = EW + (size_t)(b * TEE + t0 + srow) * HH + scol;
  const float* urow = EU + (size_t)(b * TDD + d0 + srow) * HH + scol;

  float ac0 = 0.f, ac1 = 0.f, ac2 = 0.f, ac3 = 0.f;
  float ac4 = 0.f, ac5 = 0.f, ac6 = 0.f, ac7 = 0.f;

  // prologue: stage chunk 0
  {
    float4 w0 = *(const float4*)(wrow);
    float4 w1 = *(const float4*)(wrow + 4);
    float4 u0 = *(const float4*)(urow);
    float4 u1 = *(const float4*)(urow + 4);
    *(float4*)&sw[0][srow][scol]     = w0;
    *(float4*)&sw[0][srow][scol + 4] = w1;
    *(float4*)&su[0][srow][scol]     = u0;
    *(float4*)&su[0][srow][scol + 4] = u1;
  }

  for (int ch = 0; ch < 4; ++ch) {
    float4 nw0, nw1, nu0, nu1;
    const bool more = (ch + 1) < 4;
    if (more) {                        // issue next-chunk loads BEFORE compute
      const int kn = (ch + 1) * 128;
      nw0 = *(const float4*)(wrow + kn);
      nw1 = *(const float4*)(wrow + kn + 4);
      nu0 = *(const float4*)(urow + kn);
      nu1 = *(const float4*)(urow + kn + 4);
    }
    __syncthreads();                   // buf[ch&1] writes visible

    const float (*swc)[132] = sw[ch & 1];
    const float (*suc)[132] = su[ch & 1];
    const float* vbase = Va + ch * 128;

#define TERM(W_, U_, V_, AC_) { \
    float z_ = fmaf((W_), (U_), 1.0f);           \
    float r_ = __builtin_amdgcn_rcpf(z_);        \
    AC_ = fmaf((V_), r_, AC_); }

    #pragma unroll 4
    for (int kk = 0; kk < 128; kk += 8) {
      float4 wA = *(const float4*)&swc[t][kk];
      float4 wB = *(const float4*)&swc[t][kk + 4];
      float4 uA = *(const float4*)&suc[d][kk];
      float4 uB = *(const float4*)&suc[d][kk + 4];
      float4 vA = *(const float4*)(vbase + kk);      // uniform -> s_load
      float4 vB = *(const float4*)(vbase + kk + 4);
      TERM(wA.x, uA.x, vA.x, ac0) TERM(wA.y, uA.y, vA.y, ac1)
      TERM(wA.z, uA.z, vA.z, ac2) TERM(wA.w, uA.w, vA.w, ac3)
      TERM(wB.x, uB.x, vB.x, ac4) TERM(wB.y, uB.y, vB.y, ac5)
      TERM(wB.z, uB.z, vB.z, ac6) TERM(wB.w, uB.w, vB.w, ac7)
    }
#undef TERM

    if (more) {                        // stage next chunk into other buffer
      const int nb = (ch + 1) & 1;
      *(float4*)&sw[nb][srow][scol]     = nw0;
      *(float4*)&sw[nb][srow][scol + 4] = nw1;
      *(float4*)&su[nb][srow][scol]     = nu0;
      *(float4*)&su[nb][srow][scol + 4] = nu1;
    }
  }
  float s = ((ac0 + ac1) + (ac2 + ac3)) + ((ac4 + ac5) + (ac6 + ac7));
  A[(size_t)(b * TDD + d0 + d) * TEE + t0 + t] = s;
}

// ---------- phase 3+4 fused: softmax(A) -> e; c = e @ enc via bf16 MFMA ----------
// grid (16 d-tiles, 2 h-halves, 8 b), block 256 = 4 waves.
// Each block: softmax 16 rows (redundant across y, cheap), P bf16 in LDS, MFMA.
__global__ __launch_bounds__(256) void ctx_fused(
    const float* __restrict__ A, const unsigned short* __restrict__ encT,
    float* __restrict__ c, float* __restrict__ e_out)
{
  __shared__ unsigned short pe[16][264];   // padded: 528B stride -> benign 2-way

  const int b  = blockIdx.z;
  const int d0 = blockIdx.x * 16;
  const int h0 = blockIdx.y * 256;
  const int lane = threadIdx.x & 63, w = threadIdx.x >> 6;

  // --- softmax: wave w owns rows w*4 + (lane>>4); 16 lanes per row, 16 cols each
  {
    const int row  = w * 4 + (lane >> 4);
    const int col0 = (lane & 15) * 16;
    const float* ar = A + ((size_t)(b * TDD + d0 + row)) * TEE + col0;
    float x[16];
    #pragma unroll
    for (int j = 0; j < 4; ++j) {
      float4 v = *(const float4*)(ar + j * 4);
      x[4*j] = v.x; x[4*j+1] = v.y; x[4*j+2] = v.z; x[4*j+3] = v.w;
    }
    float m = x[0];
    #pragma unroll
    for (int j = 1; j < 16; ++j) m = fminf(m, x[j]);
    #pragma unroll
    for (int off = 8; off; off >>= 1) m = fminf(m, __shfl_xor(m, off)); // 16-lane groups
    float p[16], s = 0.f;
    #pragma unroll
    for (int j = 0; j < 16; ++j) {
      p[j] = __builtin_amdgcn_exp2f(C2LOG2E * (m - x[j]));
      s += p[j];
    }
    #pragma unroll
    for (int off = 8; off; off >>= 1) s += __shfl_xor(s, off);
    float r = __builtin_amdgcn_rcpf(s);

    float* er = e_out + ((size_t)(b * TDD + d0 + row)) * TEE + col0;
    #pragma unroll
    for (int j = 0; j < 16; ++j) {
      float v = p[j] * r;
      pe[row][col0 + j] = f2bf(v);
      if (blockIdx.y == 0) er[j] = v;
    }
  }
  __syncthreads();

  // --- MFMA: wave w covers h = h0 + w*64 .. +64
  const int r15 = lane & 15, g = lane >> 4;
  const int hw = h0 + w * 64;
  floatx4 acc[4] = {{0.f,0.f,0.f,0.f},{0.f,0.f,0.f,0.f},
                    {0.f,0.f,0.f,0.f},{0.f,0.f,0.f,0.f}};
  const unsigned short* bp0 = encT + ((size_t)b * HH + hw + r15) * TEE + g * 8;

  for (int k0 = 0; k0 < TEE; k0 += 32) {
    short8 a = *(const short8*)(&pe[r15][k0 + g * 8]);
    #pragma unroll
    for (int nt = 0; nt < 4; ++nt) {
      short8 bv = *(const short8*)(bp0 + (size_t)nt * 16 * TEE + k0);
      acc[nt] = __builtin_amdgcn_mfma_f32_16x16x32_bf16(a, bv, acc[nt], 0, 0, 0);
    }
  }
  #pragma unroll
  for (int nt = 0; nt < 4; ++nt) {
    float* cp = c + (size_t)(b * TDD + d0 + g * 4) * HH + hw + nt * 16 + r15;
    #pragma unroll
    for (int r = 0; r < 4; ++r) cp[(size_t)r * HH] = acc[nt][r];
  }
}

extern "C" void kernel_launch(void* const* d_in, const int* in_sizes, int n_in,
                              void* d_out, int out_size, void* d_ws, size_t ws_size,
                              hipStream_t stream) {
  const float* enc = (const float*)d_in[0];
  const float* dec = (const float*)d_in[1];
  const float* Wa  = (const float*)d_in[2];
  const float* Ua  = (const float*)d_in[3];
  const float* Va  = (const float*)d_in[4];

  float* c_out = (float*)d_out;                          // f32 c [B*TD*H]
  float* e_out = c_out + (size_t)BB * TDD * HH;          // f32 e [B*TD*TE]

  unsigned short* WTa  = (unsigned short*)d_ws;          // bf16 512KB
  unsigned short* WTu  = WTa + (size_t)HH * HH;          // bf16 512KB
  unsigned short* encT = WTu + (size_t)HH * HH;          // bf16 2MB
  float* EW  = (float*)(encT + (size_t)BB * HH * TEE);   // f32 4MB
  float* EU  = EW + (size_t)BB * TEE * HH;               // f32 4MB
  float* Asc = EU + (size_t)BB * TDD * HH;               // f32 2MB

  prep_kernel<<<dim3(8, 8, 10),  256, 0, stream>>>(Wa, Ua, enc, WTa, WTu, encT);
  proj_exp   <<<dim3(32, 8, 2),  256, 0, stream>>>(enc, dec, WTa, WTu, EW, EU);
  score_db   <<<dim3(16, 16, 8), 256, 0, stream>>>(EW, EU, Va, Asc);
  ctx_fused  <<<dim3(16, 2, 8),  256, 0, stream>>>(Asc, encT, c_out, e_out);
}